// Round 1
// baseline (1726.822 us; speedup 1.0000x reference)
//
#include <hip/hip_runtime.h>
#include <math.h>

#define N_TOK 16384
#define DDIM  384
#define KCODE 8192
#define EMA   0.99f
#define EPS_F 1e-5f

// argmin kernel tiling
#define BM 64        // tokens per block
#define BN 128       // codes per chunk
#define DC 32        // d-chunk
#define KSPLIT 4     // code-range splits (occupancy)
#define ZS_STRIDE 68   // 64 + 4 pad (16B-aligned rows, conflict-light)
#define CS_STRIDE 132  // 128 + 4 pad

// ------- ws layout (float units) -------
// [0,        16384)   ws_idx (int)
// [16384,    24576)   counts
// [24576,  3170304)   embed_sum (K*D)
// [3170304]           sumsq (loss accum)
// [3170305]           n_acc
// [3170306, 3178498)  cnorm (K)
// [3178498, 3244034)  part_d (N*KSPLIT)
// [3244034, 3309570)  part_i (int, N*KSPLIT)
#define WS_COUNTS   16384
#define WS_EMBED    24576
#define WS_SUMSQ    3170304
#define WS_NACC     3170305
#define WS_CNORM    3170306
#define WS_PARTD    3178498
#define WS_PARTI    3244034

__global__ void cnorm_kernel(const float* __restrict__ cb, float* __restrict__ cnorm) {
    int wave = (blockIdx.x * blockDim.x + threadIdx.x) >> 6;
    int lane = threadIdx.x & 63;
    if (wave >= KCODE) return;
    const float* row = cb + wave * DDIM;
    float s = 0.f;
    #pragma unroll
    for (int r = 0; r < 6; r++) { float v = row[lane + 64 * r]; s += v * v; }
    #pragma unroll
    for (int off = 32; off > 0; off >>= 1) s += __shfl_down(s, off, 64);
    if (lane == 0) cnorm[wave] = s;
}

__launch_bounds__(256)
__global__ void argmin_kernel(const float* __restrict__ z, const float* __restrict__ cb,
                              const float* __restrict__ cnorm,
                              float* __restrict__ part_d, int* __restrict__ part_i) {
    __shared__ float zs[DC * ZS_STRIDE];
    __shared__ float cs[DC * CS_STRIDE];
    __shared__ float redd[BM * 16];
    __shared__ int   redi[BM * 16];

    const int tid = threadIdx.x;
    const int ty = tid >> 4;          // 0..15 -> token group of 4
    const int tx = tid & 15;          // 0..15 -> code group of 8
    const int m0 = blockIdx.x * BM;
    const int ks = blockIdx.y;        // 0..KSPLIT-1
    const int k_begin = ks * (KCODE / KSPLIT);
    const int k_end   = k_begin + (KCODE / KSPLIT);

    float best[4];
    int   besti[4];
    #pragma unroll
    for (int i = 0; i < 4; i++) { best[i] = 3.4e38f; besti[i] = 0; }

    for (int kc = k_begin; kc < k_end; kc += BN) {
        float acc[4][8];
        #pragma unroll
        for (int i = 0; i < 4; i++)
            #pragma unroll
            for (int j = 0; j < 8; j++) acc[i][j] = 0.f;

        for (int dc = 0; dc < DDIM; dc += DC) {
            // stage z tile transposed: zs[d][m], 512 float4
            #pragma unroll
            for (int r = 0; r < 2; r++) {
                int q = tid + r * 256;
                int m = q >> 3, c = q & 7;
                const float4 v = *reinterpret_cast<const float4*>(z + (size_t)(m0 + m) * DDIM + dc + c * 4);
                zs[(c * 4 + 0) * ZS_STRIDE + m] = v.x;
                zs[(c * 4 + 1) * ZS_STRIDE + m] = v.y;
                zs[(c * 4 + 2) * ZS_STRIDE + m] = v.z;
                zs[(c * 4 + 3) * ZS_STRIDE + m] = v.w;
            }
            // stage code tile transposed: cs[d][n], 1024 float4
            #pragma unroll
            for (int r = 0; r < 4; r++) {
                int q = tid + r * 256;
                int n = q >> 3, c = q & 7;
                const float4 v = *reinterpret_cast<const float4*>(cb + (size_t)(kc + n) * DDIM + dc + c * 4);
                cs[(c * 4 + 0) * CS_STRIDE + n] = v.x;
                cs[(c * 4 + 1) * CS_STRIDE + n] = v.y;
                cs[(c * 4 + 2) * CS_STRIDE + n] = v.z;
                cs[(c * 4 + 3) * CS_STRIDE + n] = v.w;
            }
            __syncthreads();
            #pragma unroll
            for (int d = 0; d < DC; d++) {
                float4 zf = *reinterpret_cast<const float4*>(zs + d * ZS_STRIDE + ty * 4);
                float4 c0 = *reinterpret_cast<const float4*>(cs + d * CS_STRIDE + tx * 8);
                float4 c1 = *reinterpret_cast<const float4*>(cs + d * CS_STRIDE + tx * 8 + 4);
                float zv[4] = {zf.x, zf.y, zf.z, zf.w};
                float cv[8] = {c0.x, c0.y, c0.z, c0.w, c1.x, c1.y, c1.z, c1.w};
                #pragma unroll
                for (int i = 0; i < 4; i++)
                    #pragma unroll
                    for (int j = 0; j < 8; j++)
                        acc[i][j] = fmaf(zv[i], cv[j], acc[i][j]);
            }
            __syncthreads();
        }
        // epilogue: dist = ||c||^2 - 2 z.c  (||z||^2 constant per token)
        float4 n0 = *reinterpret_cast<const float4*>(cnorm + kc + tx * 8);
        float4 n1 = *reinterpret_cast<const float4*>(cnorm + kc + tx * 8 + 4);
        float cn[8] = {n0.x, n0.y, n0.z, n0.w, n1.x, n1.y, n1.z, n1.w};
        #pragma unroll
        for (int i = 0; i < 4; i++) {
            #pragma unroll
            for (int j = 0; j < 8; j++) {
                float dist = cn[j] - 2.f * acc[i][j];
                if (dist < best[i]) { best[i] = dist; besti[i] = kc + tx * 8 + j; }
            }
        }
    }

    #pragma unroll
    for (int i = 0; i < 4; i++) {
        int tl = ty * 4 + i;
        redd[tl * 16 + tx] = best[i];
        redi[tl * 16 + tx] = besti[i];
    }
    __syncthreads();
    if (tid < BM) {
        float bd = redd[tid * 16];
        int   bi = redi[tid * 16];
        #pragma unroll
        for (int x = 1; x < 16; x++) {
            float dd = redd[tid * 16 + x];
            int   ii = redi[tid * 16 + x];
            if (dd < bd || (dd == bd && ii < bi)) { bd = dd; bi = ii; }
        }
        part_d[(size_t)(m0 + tid) * KSPLIT + ks] = bd;
        part_i[(size_t)(m0 + tid) * KSPLIT + ks] = bi;
    }
}

__global__ void merge_kernel(const float* __restrict__ pd, const int* __restrict__ pi,
                             int* __restrict__ ws_idx, float* __restrict__ out_idx) {
    int t = blockIdx.x * blockDim.x + threadIdx.x;
    if (t >= N_TOK) return;
    float bd = pd[t * KSPLIT];
    int   bi = pi[t * KSPLIT];
    #pragma unroll
    for (int x = 1; x < KSPLIT; x++) {
        float dd = pd[t * KSPLIT + x];
        int   ii = pi[t * KSPLIT + x];
        if (dd < bd || (dd == bd && ii < bi)) { bd = dd; bi = ii; }
    }
    ws_idx[t] = bi;
    out_idx[t] = (float)bi;
}

// one wave per token: gather quantized, accumulate loss, scatter EMA stats
__global__ void gather_scatter_kernel(const float* __restrict__ z, const float* __restrict__ cb,
                                      const int* __restrict__ ws_idx,
                                      float* __restrict__ out_q, float* __restrict__ embed_ws,
                                      float* __restrict__ counts, float* __restrict__ sumsq) {
    int t = (blockIdx.x * blockDim.x + threadIdx.x) >> 6;
    int lane = threadIdx.x & 63;
    if (t >= N_TOK) return;
    int k = ws_idx[t];
    const float* zr = z + (size_t)t * DDIM;
    const float* cr = cb + (size_t)k * DDIM;
    float* qr = out_q + (size_t)t * DDIM;
    float* er = embed_ws + (size_t)k * DDIM;
    float s = 0.f;
    #pragma unroll
    for (int r = 0; r < 6; r++) {
        int d = lane + 64 * r;
        float zv = zr[d];
        float qv = cr[d];
        qr[d] = qv;                     // quantized_st == quantized numerically
        float df = zv - qv;
        s += df * df;
        atomicAdd(er + d, zv);
    }
    #pragma unroll
    for (int off = 32; off > 0; off >>= 1) s += __shfl_down(s, off, 64);
    if (lane == 0) {
        atomicAdd(sumsq, s);
        atomicAdd(counts + k, 1.0f);
    }
}

__global__ void cluster_kernel(const float* __restrict__ ema_cs, const float* __restrict__ counts,
                               float* __restrict__ out_ncs, float* __restrict__ n_acc,
                               const float* __restrict__ sumsq, float* __restrict__ out_loss) {
    int i = blockIdx.x * blockDim.x + threadIdx.x;
    float v = 0.f;
    if (i < KCODE) {
        v = EMA * ema_cs[i] + (1.f - EMA) * counts[i];
        out_ncs[i] = v;
    }
    __shared__ float sm[4];
    int lane = threadIdx.x & 63, w = threadIdx.x >> 6;
    #pragma unroll
    for (int off = 32; off > 0; off >>= 1) v += __shfl_down(v, off, 64);
    if (lane == 0) sm[w] = v;
    __syncthreads();
    if (threadIdx.x == 0) {
        atomicAdd(n_acc, sm[0] + sm[1] + sm[2] + sm[3]);
        if (blockIdx.x == 0) {
            // loss = codebook_loss + 0.25*commitment = 1.25 * mean((z-q)^2)
            out_loss[0] = 1.25f * sumsq[0] / (float)(N_TOK * DDIM);
        }
    }
}

__global__ void codebook_kernel(const float* __restrict__ ema_es, const float* __restrict__ embed_ws,
                                const float* __restrict__ ncs, const float* __restrict__ n_acc,
                                float* __restrict__ out_es, float* __restrict__ out_cb) {
    int i = blockIdx.x * blockDim.x + threadIdx.x;
    if (i >= KCODE * DDIM) return;
    float es = EMA * ema_es[i] + (1.f - EMA) * embed_ws[i];
    out_es[i] = es;
    int k = i / DDIM;
    float n = n_acc[0];
    float smooth = (ncs[k] + EPS_F) / (n + (float)KCODE * EPS_F) * n;
    out_cb[i] = es / smooth;
}

extern "C" void kernel_launch(void* const* d_in, const int* in_sizes, int n_in,
                              void* d_out, int out_size, void* d_ws, size_t ws_size,
                              hipStream_t stream) {
    const float* z       = (const float*)d_in[0];
    const float* cb      = (const float*)d_in[1];
    const float* ema_cs  = (const float*)d_in[2];
    const float* ema_es  = (const float*)d_in[3];

    float* out      = (float*)d_out;
    float* out_q    = out;                       // 6291456
    float* out_idx  = out + 6291456;             // 16384
    float* out_loss = out + 6307840;             // 1
    float* out_ncs  = out + 6307841;             // 8192
    float* out_es   = out + 6316033;             // 3145728
    float* out_cb   = out + 9461761;             // 3145728

    float* ws      = (float*)d_ws;
    int*   ws_idx  = (int*)ws;
    float* counts  = ws + WS_COUNTS;
    float* embed   = ws + WS_EMBED;
    float* sumsq   = ws + WS_SUMSQ;
    float* n_acc   = ws + WS_NACC;
    float* cnorm   = ws + WS_CNORM;
    float* part_d  = ws + WS_PARTD;
    int*   part_i  = (int*)(ws + WS_PARTI);

    // zero counts, embed_sum, sumsq, n_acc in one shot
    hipMemsetAsync(counts, 0, (size_t)(WS_CNORM - WS_COUNTS) * sizeof(float), stream);

    cnorm_kernel<<<KCODE * 64 / 256, 256, 0, stream>>>(cb, cnorm);
    dim3 grid_am(N_TOK / BM, KSPLIT, 1);
    argmin_kernel<<<grid_am, 256, 0, stream>>>(z, cb, cnorm, part_d, part_i);
    merge_kernel<<<N_TOK / 256, 256, 0, stream>>>(part_d, part_i, ws_idx, out_idx);
    gather_scatter_kernel<<<N_TOK * 64 / 256, 256, 0, stream>>>(z, cb, ws_idx, out_q, embed, counts, sumsq);
    cluster_kernel<<<(KCODE + 255) / 256, 256, 0, stream>>>(ema_cs, counts, out_ncs, n_acc, sumsq, out_loss);
    codebook_kernel<<<(KCODE * DDIM) / 256, 256, 0, stream>>>(ema_es, embed, out_ncs, n_acc, out_es, out_cb);
}